// Round 2
// baseline (413.282 us; speedup 1.0000x reference)
//
#include <hip/hip_runtime.h>

#define CCH   256
#define FH    96
#define FW    96
#define SCALE 0.0625f

#define HWIN  23          // rows 0..20 data, row hwin = zero pad, row 22 = dump
#define PC    24          // padded cols = 6 float4 quads
#define CHW   (HWIN*PC)   // 552 floats per channel plane
#define CC    8           // channels per chunk
#define HALFCH 128        // channels per block (roi split across 2 blocks)
#define NCHUNK (HALFCH/CC) // 16

__global__ __launch_bounds__(256, 8)
void roialign_kernel(const float* __restrict__ feat,
                     const float* __restrict__ rois,
                     float* __restrict__ out)
{
    __shared__ __align__(16) float win[CC * CHW];   // 17.7 KB
    __shared__ int   s_lo[2][14];
    __shared__ float s_wl[2][14], s_wh[2][14];

    const int k    = blockIdx.x >> 1;
    const int half = blockIdx.x & 1;
    const int tid  = threadIdx.x;

    // ---------- Phase A: per-roi sample coordinates ----------
    const float x1 = rois[k*5+1] * SCALE;
    const float y1 = rois[k*5+2] * SCALE;
    const float x2 = rois[k*5+3] * SCALE;
    const float y2 = rois[k*5+4] * SCALE;
    const int   b  = (int)rois[k*5+0];
    const float binw = fmaxf(x2 - x1, 1.0f) * (1.0f/7.0f);
    const float binh = fmaxf(y2 - y1, 1.0f) * (1.0f/7.0f);

    if (tid < 28) {
        const int   axis  = (tid >= 14) ? 1 : 0;     // 0=y, 1=x
        const int   g     = axis ? tid - 14 : tid;
        const float start = axis ? x1 : y1;
        const float bsz   = axis ? binw : binh;
        const float offs  = (float)(g >> 1) + 0.25f + 0.5f*(float)(g & 1);
        const float coord = start + bsz * offs;
        const bool  valid = (coord >= -1.0f) && (coord <= 96.0f);
        const float cc    = fminf(fmaxf(coord, 0.0f), 95.0f);
        const float lof   = floorf(cc);
        const float frac  = cc - lof;
        const float v     = valid ? 1.0f : 0.0f;
        s_lo[axis][g] = (int)lof;
        s_wl[axis][g] = (1.0f - frac) * v;
        s_wh[axis][g] = frac * v;
    }
    __syncthreads();

    // Block-uniform window extents
    const int row0 = s_lo[0][0];
    const int col0 = s_lo[1][0] & ~3;                       // 16B-aligned window start
    const int hwin = min(s_lo[0][13] + 1, 95) - row0 + 1;   // rows actually needed (<=21)

    // Zero the pad row (index hwin) of every plane: weight-0 structural reads
    // (clamped hi) touch it; must be finite.
    for (int i = tid; i < CC*PC; i += 256) {
        const int cl  = i / PC;
        const int col = i - cl*PC;
        win[cl*CHW + hwin*PC + col] = 0.0f;
    }

    // ---------- Phase B: per-thread tap addresses & weights (chunk-invariant) ----------
    const int  pix    = tid & 63;
    const int  cg     = tid >> 6;          // wave id 0..3 -> channels cg, cg+4 of chunk
    const bool active = pix < 49;
    const int  p      = active ? pix : 0;
    const int  oy     = p / 7;
    const int  ox     = p - oy*7;

    int   addr0[4];
    float w00[4], w01[4], w10[4], w11[4];
    #pragma unroll
    for (int sy = 0; sy < 2; ++sy) {
        const int   gy  = 2*oy + sy;
        const int   rlo = s_lo[0][gy] - row0;
        const float wyl = s_wl[0][gy], wyh = s_wh[0][gy];
        #pragma unroll
        for (int sx = 0; sx < 2; ++sx) {
            const int   gx  = 2*ox + sx;
            const int   clo = s_lo[1][gx] - col0;
            const float wxl = s_wl[1][gx], wxh = s_wh[1][gx];
            const int   s   = sy*2 + sx;
            addr0[s] = cg*CHW + rlo*PC + clo;
            w00[s] = wyl*wxl;  w01[s] = wyl*wxh;
            w10[s] = wyh*wxl;  w11[s] = wyh*wxh;
        }
    }

    // ---------- load-phase lane constants ----------
    const int  lcl     = tid >> 5;         // channel slot 0..7
    const int  ll      = tid & 31;
    const int  lr0     = min(ll / 6, 4);   // row sub-index 0..4
    const int  lq      = ll - (ll/6)*6;    // quad 0..5 (lanes 30,31 dup lane 24/25's quad path)
    const bool lactive = ll < 30;
    const int  colg    = min(col0 + lq*4, FW - 4);   // clamp keeps float4 in-bounds
    const int  cbase0  = half * HALFCH;

    const float* gbase = feat + ((size_t)(b*CCH + cbase0 + lcl)*FH)*FW + colg;

    // Register staging: 5 float4 rows per lane, global->reg for chunk ch+1
    // overlaps compute of chunk ch.
    float4 stage[5];
    int    grow[5];     // global row offsets (clamped, chunk-invariant)
    int    ldst[5];     // LDS dst (dump row 22 for out-of-range), chunk-invariant
    #pragma unroll
    for (int i = 0; i < 5; ++i) {
        const int r = lr0 + 5*i;
        grow[i] = min(row0 + r, FH - 1) * FW;
        ldst[i] = lcl*CHW + ((r < hwin) ? r : 22)*PC + lq*4;
    }

    #define ISSUE_LOADS(CH)  do {                                           \
        const float* gp = gbase + (size_t)(CH)*CC*FH*FW;                    \
        _Pragma("unroll")                                                   \
        for (int i = 0; i < 5; ++i) stage[i] = *(const float4*)(gp + grow[i]); \
    } while (0)

    float* outp = out + ((size_t)k*CCH + cbase0 + cg)*49 + p;

    if (lactive) ISSUE_LOADS(0);

    for (int ch = 0; ch < NCHUNK; ++ch) {
        if (ch) __syncthreads();           // prev chunk's LDS fully consumed
        if (lactive) {
            #pragma unroll
            for (int i = 0; i < 5; ++i)    // vmcnt wait lands here
                *(float4*)&win[ldst[i]] = stage[i];
        }
        __syncthreads();

        if (ch + 1 < NCHUNK && lactive) ISSUE_LOADS(ch + 1);   // in flight during compute

        if (active) {
            float acc0 = 0.0f, acc1 = 0.0f;
            #pragma unroll
            for (int s = 0; s < 4; ++s) {
                const int a  = addr0[s];
                const int a2 = a + 4*CHW;
                acc0 += w00[s]*win[a]      + w01[s]*win[a+1]
                      + w10[s]*win[a+PC]   + w11[s]*win[a+PC+1];
                acc1 += w00[s]*win[a2]     + w01[s]*win[a2+1]
                      + w10[s]*win[a2+PC]  + w11[s]*win[a2+PC+1];
            }
            outp[0]    = acc0 * 0.25f;
            outp[4*49] = acc1 * 0.25f;
        }
        outp += CC*49;
    }
    #undef ISSUE_LOADS
}

extern "C" void kernel_launch(void* const* d_in, const int* in_sizes, int n_in,
                              void* d_out, int out_size, void* d_ws, size_t ws_size,
                              hipStream_t stream) {
    const float* feat = (const float*)d_in[0];
    const float* rois = (const float*)d_in[1];
    float*       outp = (float*)d_out;
    const int K = in_sizes[1] / 5;   // 1024
    roialign_kernel<<<K*2, 256, 0, stream>>>(feat, rois, outp);
}

// Round 3
// 195.786 us; speedup vs baseline: 2.1109x; 2.1109x over previous
//
#include <hip/hip_runtime.h>

#define CCH   256
#define FH    96
#define FW    96
#define SCALE 0.0625f

#define HWIN  23          // rows 0..20 data, row hwin = zero pad, row 22 = dump
#define PC    24          // padded cols = 6 float4 quads
#define CHW   (HWIN*PC)   // 552 floats per channel plane
#define CC    8           // channels per chunk
#define HALFCH 128        // channels per block (roi split across 2 blocks)
#define NCHUNK (HALFCH/CC) // 16

// (256,4): 128 VGPR/wave budget. (256,8) capped at 64 VGPR and spilled the
// staging registers to scratch -> +630 MB HBM each way, 3.9x regression (R2).
__global__ __launch_bounds__(256, 4)
void roialign_kernel(const float* __restrict__ feat,
                     const float* __restrict__ rois,
                     float* __restrict__ out)
{
    __shared__ __align__(16) float win[CC * CHW];   // 17.7 KB
    __shared__ int   s_lo[2][14];
    __shared__ float s_wl[2][14], s_wh[2][14];

    const int k    = blockIdx.x >> 1;
    const int half = blockIdx.x & 1;
    const int tid  = threadIdx.x;

    // ---------- Phase A: per-roi sample coordinates ----------
    const float x1 = rois[k*5+1] * SCALE;
    const float y1 = rois[k*5+2] * SCALE;
    const float x2 = rois[k*5+3] * SCALE;
    const float y2 = rois[k*5+4] * SCALE;
    const int   b  = (int)rois[k*5+0];
    const float binw = fmaxf(x2 - x1, 1.0f) * (1.0f/7.0f);
    const float binh = fmaxf(y2 - y1, 1.0f) * (1.0f/7.0f);

    if (tid < 28) {
        const int   axis  = (tid >= 14) ? 1 : 0;     // 0=y, 1=x
        const int   g     = axis ? tid - 14 : tid;
        const float start = axis ? x1 : y1;
        const float bsz   = axis ? binw : binh;
        const float offs  = (float)(g >> 1) + 0.25f + 0.5f*(float)(g & 1);
        const float coord = start + bsz * offs;
        const bool  valid = (coord >= -1.0f) && (coord <= 96.0f);
        const float cc    = fminf(fmaxf(coord, 0.0f), 95.0f);
        const float lof   = floorf(cc);
        const float frac  = cc - lof;
        const float v     = valid ? 1.0f : 0.0f;
        s_lo[axis][g] = (int)lof;
        s_wl[axis][g] = (1.0f - frac) * v;
        s_wh[axis][g] = frac * v;
    }
    __syncthreads();

    // Block-uniform window extents
    const int row0 = s_lo[0][0];
    const int col0 = s_lo[1][0] & ~3;                       // 16B-aligned window start
    const int hwin = min(s_lo[0][13] + 1, 95) - row0 + 1;   // rows actually needed (<=21)

    // Zero the pad row (index hwin) of every plane: weight-0 structural reads
    // (clamped hi) touch it; must be finite.
    for (int i = tid; i < CC*PC; i += 256) {
        const int cl  = i / PC;
        const int col = i - cl*PC;
        win[cl*CHW + hwin*PC + col] = 0.0f;
    }

    // ---------- Phase B: per-thread tap addresses & weights (chunk-invariant) ----------
    const int  pix    = tid & 63;
    const int  cg     = tid >> 6;          // wave id 0..3 -> channels cg, cg+4 of chunk
    const bool active = pix < 49;
    const int  p      = active ? pix : 0;
    const int  oy     = p / 7;
    const int  ox     = p - oy*7;

    int   addr0[4];
    float w00[4], w01[4], w10[4], w11[4];
    #pragma unroll
    for (int sy = 0; sy < 2; ++sy) {
        const int   gy  = 2*oy + sy;
        const int   rlo = s_lo[0][gy] - row0;
        const float wyl = s_wl[0][gy], wyh = s_wh[0][gy];
        #pragma unroll
        for (int sx = 0; sx < 2; ++sx) {
            const int   gx  = 2*ox + sx;
            const int   clo = s_lo[1][gx] - col0;
            const float wxl = s_wl[1][gx], wxh = s_wh[1][gx];
            const int   s   = sy*2 + sx;
            addr0[s] = cg*CHW + rlo*PC + clo;
            w00[s] = wyl*wxl;  w01[s] = wyl*wxh;
            w10[s] = wyh*wxl;  w11[s] = wyh*wxh;
        }
    }

    // ---------- load-phase lane constants ----------
    const int  lcl     = tid >> 5;         // channel slot 0..7
    const int  ll      = tid & 31;
    const int  lr0     = min(ll / 6, 4);   // row sub-index 0..4
    const int  lq      = ll - (ll/6)*6;    // quad 0..5
    const bool lactive = ll < 30;
    const int  colg    = min(col0 + lq*4, FW - 4);   // clamp keeps float4 in-bounds
    const int  cbase0  = half * HALFCH;

    const float* gbase = feat + ((size_t)(b*CCH + cbase0 + lcl)*FH)*FW + colg;

    // Chunk-invariant global row offsets (clamped) and LDS dests (dump row 22
    // for rows beyond hwin). Named scalars: must never touch scratch.
    const int g0 = min(row0 + lr0      , FH-1) * FW;
    const int g1 = min(row0 + lr0 +  5 , FH-1) * FW;
    const int g2 = min(row0 + lr0 + 10 , FH-1) * FW;
    const int g3 = min(row0 + lr0 + 15 , FH-1) * FW;
    const int g4 = min(row0 + lr0 + 20 , FH-1) * FW;
    const int dbase = lcl*CHW + lq*4;
    const int d0 = dbase + ((lr0      < hwin) ? (lr0     ) : 22)*PC;
    const int d1 = dbase + ((lr0 +  5 < hwin) ? (lr0 +  5) : 22)*PC;
    const int d2 = dbase + ((lr0 + 10 < hwin) ? (lr0 + 10) : 22)*PC;
    const int d3 = dbase + ((lr0 + 15 < hwin) ? (lr0 + 15) : 22)*PC;
    const int d4 = dbase + ((lr0 + 20 < hwin) ? (lr0 + 20) : 22)*PC;

    float4 s0, s1, s2, s3, s4;

    #define ISSUE_LOADS(CH)  do {                                   \
        const float* gp = gbase + (size_t)(CH)*CC*FH*FW;            \
        s0 = *(const float4*)(gp + g0);                             \
        s1 = *(const float4*)(gp + g1);                             \
        s2 = *(const float4*)(gp + g2);                             \
        s3 = *(const float4*)(gp + g3);                             \
        s4 = *(const float4*)(gp + g4);                             \
    } while (0)

    float* outp = out + ((size_t)k*CCH + cbase0 + cg)*49 + p;

    if (lactive) ISSUE_LOADS(0);

    for (int ch = 0; ch < NCHUNK; ++ch) {
        if (ch) __syncthreads();           // prev chunk's LDS fully consumed
        if (lactive) {
            *(float4*)&win[d0] = s0;       // vmcnt wait lands here
            *(float4*)&win[d1] = s1;
            *(float4*)&win[d2] = s2;
            *(float4*)&win[d3] = s3;
            *(float4*)&win[d4] = s4;
        }
        __syncthreads();

        if (ch + 1 < NCHUNK && lactive) ISSUE_LOADS(ch + 1);   // in flight during compute

        if (active) {
            float acc0 = 0.0f, acc1 = 0.0f;
            #pragma unroll
            for (int s = 0; s < 4; ++s) {
                const int a  = addr0[s];
                const int a2 = a + 4*CHW;
                acc0 += w00[s]*win[a]      + w01[s]*win[a+1]
                      + w10[s]*win[a+PC]   + w11[s]*win[a+PC+1];
                acc1 += w00[s]*win[a2]     + w01[s]*win[a2+1]
                      + w10[s]*win[a2+PC]  + w11[s]*win[a2+PC+1];
            }
            outp[0]    = acc0 * 0.25f;
            outp[4*49] = acc1 * 0.25f;
        }
        outp += CC*49;
    }
    #undef ISSUE_LOADS
}

extern "C" void kernel_launch(void* const* d_in, const int* in_sizes, int n_in,
                              void* d_out, int out_size, void* d_ws, size_t ws_size,
                              hipStream_t stream) {
    const float* feat = (const float*)d_in[0];
    const float* rois = (const float*)d_in[1];
    float*       outp = (float*)d_out;
    const int K = in_sizes[1] / 5;   // 1024
    roialign_kernel<<<K*2, 256, 0, stream>>>(feat, rois, outp);
}

// Round 5
// 135.600 us; speedup vs baseline: 3.0478x; 1.4438x over previous
//
#include <hip/hip_runtime.h>

#define CCH   256
#define FH    96
#define FW    96
#define HW    (FH*FW)
#define SCALE 0.0625f

#define HROWS 21           // max window rows (span<=19 -> 21); hwin clamped to this
#define PSTR  28           // LDS row stride (floats); cols 24..27 = zeroed pad
#define PLANE (HROWS*PSTR) // 588 floats per wave plane
#define WCH   32           // channels per wave (block = 128ch half-roi, 4 waves)

// Wave-autonomous: each wave owns one LDS plane + 32 channels; no barriers in
// the main loop (within-wave ds ordering is program-order). Every address is
// clamped in-bounds BY CONSTRUCTION (R4 crashed: predicated-only safety).
__global__ __launch_bounds__(256, 8)
void roialign_kernel(const float* __restrict__ feat,
                     const float* __restrict__ rois,
                     float* __restrict__ out)
{
    __shared__ __align__(16) float win[4 * PLANE];
    __shared__ int   s_lo[2][14];
    __shared__ float s_wl[2][14], s_wh[2][14];

    const int k    = blockIdx.x >> 1;
    const int half = blockIdx.x & 1;
    const int tid  = threadIdx.x;
    const int w    = tid >> 6;
    const int ll   = tid & 63;

    // ---------- Phase A: per-roi sample coords ----------
    const float x1 = rois[k*5+1] * SCALE;
    const float y1 = rois[k*5+2] * SCALE;
    const float x2 = rois[k*5+3] * SCALE;
    const float y2 = rois[k*5+4] * SCALE;
    const int   b  = (int)rois[k*5+0];
    const float binw = fmaxf(x2 - x1, 1.0f) * (1.0f/7.0f);
    const float binh = fmaxf(y2 - y1, 1.0f) * (1.0f/7.0f);

    if (tid < 28) {
        const int   axis  = (tid >= 14) ? 1 : 0;
        const int   g     = axis ? tid - 14 : tid;
        const float start = axis ? x1 : y1;
        const float bsz   = axis ? binw : binh;
        const float offs  = (float)(g >> 1) + 0.25f + 0.5f*(float)(g & 1);
        const float coord = start + bsz * offs;
        const bool  valid = (coord >= -1.0f) && (coord <= 96.0f);
        const float cc    = fminf(fmaxf(coord, 0.0f), 95.0f);
        const float lof   = floorf(cc);
        const float frac  = cc - lof;
        const float v     = valid ? 1.0f : 0.0f;
        s_lo[axis][g] = (int)lof;
        s_wl[axis][g] = (1.0f - frac) * v;
        s_wh[axis][g] = frac * v;
    }
    __syncthreads();   // the ONLY barrier

    const int row0 = s_lo[0][0];
    const int col0 = min(s_lo[1][0] & ~3, FW - 24);   // 24-col window always in-image
    int hw_        = min(s_lo[0][13] + 1, FH-1) - row0 + 1;
    const int hwin = min(hw_, HROWS);                 // defensive clamp
    const int nslot = hwin * 6;                       // float4 slots, <=126

    float* const wp = &win[w * PLANE];

    // Zero this wave's plane once: pad cols 24..27 must be finite (weight-0
    // taps can read col clo+1==24 when xlo clamps at 95).
    {
        const float4 z = make_float4(0.f, 0.f, 0.f, 0.f);
        #pragma unroll
        for (int j = 0; j < 3; ++j) {
            const int q = ll + 64*j;
            if (q < PLANE/4) *(float4*)&wp[q*4] = z;
        }
    }

    // ---------- Phase B: tap addresses & pre-scaled weights (channel-invariant) ----------
    const bool active = ll < 49;
    const int  p  = active ? ll : 0;
    const int  oy = p / 7;
    const int  ox = p - oy*7;

    int   aL[4], aH[4];
    float w00[4], w01[4], w10[4], w11[4];
    #pragma unroll
    for (int sy = 0; sy < 2; ++sy) {
        const int   gy  = 2*oy + sy;
        const int   rlo = min(s_lo[0][gy] - row0,                 HROWS-1);
        const int   rhi = min(min(s_lo[0][gy]+1, FH-1) - row0,    HROWS-1);
        const float wyl = s_wl[0][gy], wyh = s_wh[0][gy];
        #pragma unroll
        for (int sx = 0; sx < 2; ++sx) {
            const int   gx  = 2*ox + sx;
            const int   clo = min(s_lo[1][gx] - col0, PSTR-2);    // <=23 provable; clamp anyway
            const float wxl = s_wl[1][gx], wxh = s_wh[1][gx];
            const int   s   = sy*2 + sx;
            aL[s] = rlo*PSTR + clo;
            aH[s] = rhi*PSTR + clo;
            w00[s] = wyl*wxl*0.25f;  w01[s] = wyl*wxh*0.25f;   // 0.25 = sample mean
            w10[s] = wyh*wxl*0.25f;  w11[s] = wyh*wxh*0.25f;
        }
    }

    // ---------- load-slot constants: slots ll and ll+64 of nslot ----------
    const int  sl1 = ll + 64;
    const int  r0  = ll  / 6, q0 = ll  - r0*6;
    const int  r1  = sl1 / 6, q1 = sl1 - r1*6;
    const bool L0  = ll  < nslot;
    const bool L1  = sl1 < nslot;
    // Clamped: legal addresses even for predicated-off lanes.
    const int  goff0 = min(row0 + r0, FH-1)*FW + col0 + q0*4;
    const int  goff1 = min(row0 + r1, FH-1)*FW + col0 + q1*4;
    const int  ld0   = min(r0, HROWS-1)*PSTR + q0*4;
    const int  ld1   = min(r1, HROWS-1)*PSTR + q1*4;

    const int    cb   = half*128 + w*WCH;
    const float* gch  = feat + (size_t)(b*CCH + cb) * HW;
    float*       outp = out  + ((size_t)k*CCH + cb)*49 + p;

    float4 st0, st1;
    if (L0) st0 = *(const float4*)(gch + goff0);
    if (L1) st1 = *(const float4*)(gch + goff1);

    for (int c = 0; c < WCH; ++c) {
        // vmcnt wait for this channel's loads lands on these writes; within-wave
        // ds ordering guarantees prior iteration's reads see old data first.
        if (L0) *(float4*)&wp[ld0] = st0;
        if (L1) *(float4*)&wp[ld1] = st1;

        if (c + 1 < WCH) {                       // next channel in flight during compute
            const float* gn = gch + (size_t)(c+1)*HW;
            if (L0) st0 = *(const float4*)(gn + goff0);
            if (L1) st1 = *(const float4*)(gn + goff1);
        }

        if (active) {
            float acc = 0.0f;
            #pragma unroll
            for (int s = 0; s < 4; ++s) {
                acc += w00[s]*wp[aL[s]]   + w01[s]*wp[aL[s]+1]
                     + w10[s]*wp[aH[s]]   + w11[s]*wp[aH[s]+1];
            }
            outp[0] = acc;
        }
        outp += 49;
    }
}

extern "C" void kernel_launch(void* const* d_in, const int* in_sizes, int n_in,
                              void* d_out, int out_size, void* d_ws, size_t ws_size,
                              hipStream_t stream) {
    const float* feat = (const float*)d_in[0];
    const float* rois = (const float*)d_in[1];
    float*       outp = (float*)d_out;
    const int K = in_sizes[1] / 5;   // 1024
    roialign_kernel<<<K*2, 256, 0, stream>>>(feat, rois, outp);
}